// Round 13
// baseline (621.152 us; speedup 1.0000x reference)
//
#include <hip/hip_runtime.h>

typedef float f32x4 __attribute__((ext_vector_type(4)));
typedef __bf16 bf16x8 __attribute__((ext_vector_type(8)));
typedef unsigned short u16;
typedef u16 u16x8 __attribute__((ext_vector_type(8)));

// Octonion sign table from Cayley-Dickson (levels=3): OSGN[i][j] = sign of e_i*e_j.
__constant__ float c_osgn[64] = {
  1, 1, 1, 1, 1, 1, 1, 1,
  1,-1, 1,-1, 1,-1,-1, 1,
  1,-1,-1, 1, 1, 1,-1,-1,
  1, 1,-1,-1, 1,-1, 1,-1,
  1,-1,-1,-1,-1, 1, 1, 1,
  1, 1,-1, 1,-1,-1,-1, 1,
  1, 1, 1,-1,-1, 1,-1,-1,
  1,-1, 1, 1,-1,-1, 1,-1
};

__device__ __forceinline__ u16 f2bf(float f) {
  union { float f; unsigned u; } v; v.f = f;
  unsigned u = v.u;
  return (u16)((u + 0x7fffu + ((u >> 16) & 1u)) >> 16);
}
__device__ __forceinline__ float bf2f(u16 h) {
  union { unsigned u; float f; } v; v.u = ((unsigned)h) << 16;
  return v.f;
}

typedef const __attribute__((address_space(1))) void* as1cv;
typedef __attribute__((address_space(3))) void* as3v;
__device__ __forceinline__ void load16_lds(const void* g, void* l) {
  __builtin_amdgcn_global_load_lds((as1cv)g, (as3v)l, 16, 0, 0);
}

// ---------------- converts ----------------
__global__ void conv_f32_bf16_vec(const float* __restrict__ src, u16* __restrict__ dst) {
  int i = blockIdx.x * 256 + threadIdx.x;       // over n/4 exact
  float4 v = ((const float4*)src)[i];
  ushort4 o; o.x = f2bf(v.x); o.y = f2bf(v.y); o.z = f2bf(v.z); o.w = f2bf(v.w);
  ((ushort4*)dst)[i] = o;
}

// 4 weight tensors W[w][p][q] (f32) -> Wt[w][q][p] (bf16), LDS-tiled, one launch.
__global__ __launch_bounds__(256) void transpose_w4(
    const float* __restrict__ Wq, const float* __restrict__ Wk,
    const float* __restrict__ Wv, const float* __restrict__ Wo,
    u16* __restrict__ WtB, long wsz) {
  __shared__ float t[64][65];
  const int zw = blockIdx.z;
  const int wsel = zw >> 3, w = zw & 7;
  const float* W = (wsel == 0) ? Wq : (wsel == 1) ? Wk : (wsel == 2) ? Wv : Wo;
  u16* Wt = WtB + wsel * wsz;
  const int p0 = blockIdx.y * 64, q0 = blockIdx.x * 64;
  const float* src = W + ((long)w * 512 + p0) * 512 + q0;
  const int tid = threadIdx.x;
  const int r = tid >> 2, c0 = (tid & 3) * 16;
#pragma unroll
  for (int j = 0; j < 4; j++) {
    float4 v = *(const float4*)(src + (long)r * 512 + c0 + j * 4);
    t[r][c0 + j * 4 + 0] = v.x; t[r][c0 + j * 4 + 1] = v.y;
    t[r][c0 + j * 4 + 2] = v.z; t[r][c0 + j * 4 + 3] = v.w;
  }
  __syncthreads();
  u16* dst = Wt + ((long)w * 512 + q0) * 512 + p0;
#pragma unroll
  for (int j = 0; j < 2; j++) {
    u16x8 o;
#pragma unroll
    for (int k = 0; k < 8; k++) o[k] = f2bf(t[c0 + j * 8 + k][r]);
    *(u16x8*)(dst + (long)r * 512 + c0 + j * 8) = o;
  }
}

// mixer_W[w][d][e] -> Wmt[w][e][d] * beta[e]
__global__ void transpose_wm(const float* __restrict__ W, const float* __restrict__ beta,
                             u16* __restrict__ Wt) {
  int idx = blockIdx.x * 256 + threadIdx.x;     // 8*128*128 exact
  int w = idx >> 14, rem = idx & 16383;
  int e = rem >> 7, d = rem & 127;
  Wt[(w << 14) + (e << 7) + d] = f2bf(W[(w << 14) + (d << 7) + e] * beta[e]);
}

// ---------------- fused QKV oct GEMM v3: 128x64 tile, z-fused, single-buffer, 4 blocks/CU ----
// BM=128, BN=64, BK=64. 4 waves (2M x 2N), wave tile 64x32, 48 MFMA/wave/step (3 z).
// LDS 40 KB (A 16K + B 3x8K) -> 4 blocks/CU (16 waves). m97 schedule:
// stage(gload_lds) -> sync -> compute -> sync. Inter-block backfill hides drains.
__global__ __launch_bounds__(256, 4) void oct_gemmQKV3(
    const u16* __restrict__ A, const u16* __restrict__ WtB,
    u16* __restrict__ out0, u16* __restrict__ out1, u16* __restrict__ out2,
    const float* __restrict__ fc, const float* __restrict__ fs, long wsz)
{
  __shared__ u16 smem[20480];   // As: [0..8191]; Bs z: 8192 + z*4096

  const int nwg = gridDim.x * gridDim.y;            // 1024
  const int lin = blockIdx.y * gridDim.x + blockIdx.x;
  const int swz = (lin & 7) * (nwg >> 3) + (lin >> 3);
  const int bx = swz % gridDim.x, by = swz / gridDim.x;

  const int np = bx * 64;             // 0..4032
  const int bi = np >> 9;
  const int nsub = np & 511;
  const int bm = by * 128;
  const int h = np >> 7;
  const int dbase = np & 64;          // 0 or 64: d-offset within head

  const int tid = threadIdx.x;
  const int lane = tid & 63, w = tid >> 6;
  const int l15 = lane & 15, lg = lane >> 4;
  const int wm = w >> 1, wn = w & 1;  // wave tile: rows wm*64, cols wn*32
  const int srow = lane >> 3;
  const int sgr  = (lane & 7) ^ srow;

  f32x4 acc[3][4][2];
#pragma unroll
  for (int z = 0; z < 3; z++)
#pragma unroll
    for (int a = 0; a < 4; a++)
#pragma unroll
      for (int b = 0; b < 2; b++) acc[z][a][b] = f32x4{0.f, 0.f, 0.f, 0.f};

  for (int t = 0; t < 64; ++t) {
    const int k0 = t << 6;
    const int bj = t >> 3;
    const int widx = bi ^ bj;
    const unsigned xm = (c_osgn[bj * 8 + widx] < 0.f) ? 0x80008000u : 0u;
    const long woff = (long)widx * 262144 + (k0 & 511);

    // stage: A 4 + B 3z x 2 DMA/thread
#pragma unroll
    for (int i = 0; i < 4; i++) {
      const int r = (w * 4 + i) * 8;
      load16_lds(A + (long)(bm + r + srow) * 4096 + k0 + sgr * 8,
                 (void*)(smem + r * 64));
    }
#pragma unroll
    for (int z = 0; z < 3; z++) {
      const u16* Wsrc = WtB + (long)z * wsz + woff;
#pragma unroll
      for (int i = 0; i < 2; i++) {
        const int r = (w * 2 + i) * 8;
        load16_lds(Wsrc + (long)(nsub + r + srow) * 512 + sgr * 8,
                   (void*)(smem + 8192 + z * 4096 + r * 64));
      }
    }
    __syncthreads();

#pragma unroll
    for (int kk = 0; kk < 2; kk++) {
      const int gsw = ((4 * kk + lg) ^ (l15 & 7)) * 8;
      uint4 a4[4];
#pragma unroll
      for (int mt = 0; mt < 4; mt++)
        a4[mt] = *(const uint4*)(smem + (wm * 64 + mt * 16 + l15) * 64 + gsw);
      if (xm) {
#pragma unroll
        for (int mt = 0; mt < 4; mt++) {
          a4[mt].x ^= xm; a4[mt].y ^= xm; a4[mt].z ^= xm; a4[mt].w ^= xm;
        }
      }
#pragma unroll
      for (int z = 0; z < 3; z++) {
        bf16x8 bF[2];
#pragma unroll
        for (int nt = 0; nt < 2; nt++)
          bF[nt] = *(const bf16x8*)(smem + 8192 + z * 4096 +
                                    (wn * 32 + nt * 16 + l15) * 64 + gsw);
#pragma unroll
        for (int mt = 0; mt < 4; mt++)
#pragma unroll
          for (int nt = 0; nt < 2; nt++)
            acc[z][mt][nt] = __builtin_amdgcn_mfma_f32_16x16x32_bf16(
                *(const bf16x8*)&a4[mt], bF[nt], acc[z][mt][nt], 0, 0, 0);
      }
    }
    __syncthreads();
  }

  // ---- epilogue: rope q, rope k ----
#pragma unroll
  for (int z = 0; z < 2; z++) {
    u16* dq = (z == 0) ? out0 : out1;
#pragma unroll
    for (int mt = 0; mt < 4; mt++)
#pragma unroll
      for (int nt = 0; nt < 2; nt++) {
        const int d = dbase + wn * 32 + nt * 16 + l15;
        const int p = d >> 1;
        const bool ev = (l15 & 1) == 0;
#pragma unroll
        for (int j = 0; j < 4; j++) {
          const int trow = bm + wm * 64 + mt * 16 + 4 * lg + j;
          const float v = acc[z][mt][nt][j];
          const float sh = __shfl_xor(v, 1);
          const float c = fc[trow * 64 + p];
          const float s = fs[trow * 64 + p];
          const float o = ev ? (v * c - sh * s) : (sh * s + v * c);
          dq[((long)h * 2048 + trow) * 128 + d] = f2bf(o);
        }
      }
  }

  // ---- epilogue: v transposed [H][D][T] via LDS bounce [64][136] ----
#pragma unroll
  for (int mt = 0; mt < 4; mt++)
#pragma unroll
    for (int nt = 0; nt < 2; nt++)
#pragma unroll
      for (int j = 0; j < 4; j++)
        smem[(wn * 32 + nt * 16 + l15) * 136 + wm * 64 + mt * 16 + 4 * lg + j] =
            f2bf(acc[2][mt][nt][j]);
  __syncthreads();
  {
    const int dl = tid >> 2;          // 0..63
    const int tc = (tid & 3) * 32;    // 0,32,64,96
#pragma unroll
    for (int q = 0; q < 4; q++) {
      u16x8 o = *(const u16x8*)(smem + dl * 136 + tc + q * 8);
      *(u16x8*)(out2 + ((long)h * 128 + dbase + dl) * 2048 + bm + tc + q * 8) = o;
    }
  }
}

// ---------------- oct GEMM, m97 structure: 128x128, BK=64, single-buffer ----------------
template <int MODE>
__global__ __launch_bounds__(256, 3) void oct_gemm128(
    const u16* __restrict__ A, const u16* __restrict__ WtB,
    void* __restrict__ out0,
    int K, int lda, int ldo,
    int slab_shift, int bs_shift, long wslab, long oslab, long acolslab)
{
  __shared__ u16 smem[16384];
  const int NT = K >> 6;
  const int BS = 1 << bs_shift;
  const long wblk = (long)BS * BS;

  const int nwg = gridDim.x * gridDim.y;
  const int lin = blockIdx.y * gridDim.x + blockIdx.x;
  const int swz = (lin & 7) * (nwg >> 3) + (lin >> 3);
  const int bx = swz % gridDim.x, by = swz / gridDim.x;

  const int nglob = bx * 128;
  const int z = nglob >> slab_shift;
  const int np = nglob & ((1 << slab_shift) - 1);
  const int bi = np >> bs_shift;
  const int nsub = np & (BS - 1);
  const int bm = by * 128;
  const u16* Wt = WtB + (long)z * wslab;
  const long acol0 = (long)z * acolslab;

  const int tid = threadIdx.x;
  const int lane = tid & 63, w = tid >> 6;
  const int l15 = lane & 15, lg = lane >> 4;
  const int wm = w >> 1, wn = w & 1;
  const int srow = lane >> 3;
  const int sgr  = (lane & 7) ^ srow;

  f32x4 acc[4][4];
#pragma unroll
  for (int a = 0; a < 4; a++)
#pragma unroll
    for (int b = 0; b < 4; b++) acc[a][b] = f32x4{0.f, 0.f, 0.f, 0.f};

  for (int t = 0; t < NT; ++t) {
    const int k0 = t << 6;
    const int bj = k0 >> bs_shift;
    const int widx = bi ^ bj;
    const unsigned xm = (c_osgn[bj * 8 + widx] < 0.f) ? 0x80008000u : 0u;
    const u16* Wsrc = Wt + (long)widx * wblk + (k0 & (BS - 1));

#pragma unroll
    for (int i = 0; i < 4; i++) {
      const int r = (w * 4 + i) * 8;
      load16_lds(A + (long)(bm + r + srow) * lda + acol0 + k0 + sgr * 8,
                 (void*)(smem + r * 64));
    }
#pragma unroll
    for (int i = 0; i < 4; i++) {
      const int r = (w * 4 + i) * 8;
      load16_lds(Wsrc + (long)(nsub + r + srow) * BS + sgr * 8,
                 (void*)(smem + 8192 + r * 64));
    }
    __syncthreads();

#pragma unroll
    for (int kk = 0; kk < 64; kk += 32) {
      const int gsw = (((kk >> 3) + lg) ^ (l15 & 7)) * 8;
      uint4 a4[4];
      bf16x8 bF[4];
#pragma unroll
      for (int mt = 0; mt < 4; mt++)
        a4[mt] = *(const uint4*)(smem + (wm * 64 + mt * 16 + l15) * 64 + gsw);
      if (xm) {
#pragma unroll
        for (int mt = 0; mt < 4; mt++) {
          a4[mt].x ^= xm; a4[mt].y ^= xm; a4[mt].z ^= xm; a4[mt].w ^= xm;
        }
      }
#pragma unroll
      for (int nt = 0; nt < 4; nt++)
        bF[nt] = *(const bf16x8*)(smem + 8192 + (wn * 64 + nt * 16 + l15) * 64 + gsw);
#pragma unroll
      for (int mt = 0; mt < 4; mt++)
#pragma unroll
        for (int nt = 0; nt < 4; nt++)
          acc[mt][nt] = __builtin_amdgcn_mfma_f32_16x16x32_bf16(
              *(const bf16x8*)&a4[mt], bF[nt], acc[mt][nt], 0, 0, 0);
    }
    __syncthreads();
  }

#pragma unroll
  for (int mt = 0; mt < 4; mt++)
#pragma unroll
    for (int nt = 0; nt < 4; nt++)
#pragma unroll
      for (int j = 0; j < 4; j++) {
        const int row = bm + wm * 64 + mt * 16 + 4 * lg + j;
        const int col = np + wn * 64 + nt * 16 + l15;
        const float v = acc[mt][nt][j];
        if constexpr (MODE == 0)
          ((u16*)out0)[(long)z * oslab + (long)row * ldo + col] = f2bf(v);
        else
          ((float*)out0)[(long)row * ldo + col] = v;
      }
}

// ---------------- flash attention v5: fixed-max softmax + lsum via ones-MFMA ----------------
__global__ __launch_bounds__(256, 2) void attn5(
    const u16* __restrict__ qR, const u16* __restrict__ kR,
    const u16* __restrict__ vT, u16* __restrict__ y)
{
  const int bid = blockIdx.x;
  const int h = bid & 31;
  const int qb = 31 - (bid >> 5);        // longest blocks dispatched first
  const int q0 = qb * 64;

  const int tid = threadIdx.x;
  const int lane = tid & 63, w = tid >> 6;
  const int l15 = lane & 15, lg = lane >> 4;

  __shared__ u16 Ks[2][64][128];
  __shared__ u16 Vs[2][128][64];
  __shared__ u16 Ps[4][16][64];

  auto stageK = [&](int kb, int buf) {
    const long kbase = (long)h * 2048 + (long)kb * 64;
#pragma unroll
    for (int i = 0; i < 4; i++) {
      const int j = w * 4 + i;
      const int row = j * 4 + (lane >> 4);
      const int sg = (lane & 15) ^ (row & 7);
      load16_lds(kR + (kbase + row) * 128 + sg * 8, (void*)&Ks[buf][j * 4][0]);
    }
  };
  auto stageV = [&](int kb, int buf) {
    const long vbase = (long)h * 128 * 2048 + (long)kb * 64;
#pragma unroll
    for (int i = 0; i < 4; i++) {
      const int j = w * 4 + i;
      const int row = j * 8 + (lane >> 3);
      const int sg = (lane & 7) ^ (row & 7);
      load16_lds(vT + vbase + (long)row * 2048 + sg * 8, (void*)&Vs[buf][j * 8][0]);
    }
  };

  stageK(0, 0);
  stageV(0, 0);

  bf16x8 aQ[4];
  {
    const long qbase = ((long)h * 2048 + q0 + w * 16 + l15) * 128;
#pragma unroll
    for (int c = 0; c < 4; c++)
      aQ[c] = *(const bf16x8*)(qR + qbase + 32 * c + 8 * lg);
  }

  bf16x8 ones;
#pragma unroll
  for (int j = 0; j < 8; j++) ones[j] = (__bf16)1.0f;

  f32x4 Y[8], LS;
#pragma unroll
  for (int dt = 0; dt < 8; dt++) Y[dt] = f32x4{0.f, 0.f, 0.f, 0.f};
  LS = f32x4{0.f, 0.f, 0.f, 0.f};

  const float scale = 0.08838834764831845f;   // 1/sqrt(128)
  const int nkb = qb + 1;

  for (int kb = 0; kb < nkb; kb++) {
    const int buf = kb & 1;
    const int k0 = kb * 64;
    if (kb + 1 < nkb) { stageK(kb + 1, buf ^ 1); stageV(kb + 1, buf ^ 1); }
    if (kb + 1 < nkb) asm volatile("s_waitcnt vmcnt(8)" ::: "memory");
    else              asm volatile("s_waitcnt vmcnt(0)" ::: "memory");
    __builtin_amdgcn_s_barrier();
    asm volatile("" ::: "memory");

    // ---- QK^T ----
    f32x4 S[4];
#pragma unroll
    for (int ks = 0; ks < 4; ks++) S[ks] = f32x4{0.f, 0.f, 0.f, 0.f};
#pragma unroll
    for (int c = 0; c < 4; c++) {
      bf16x8 bK[4];
#pragma unroll
      for (int ks = 0; ks < 4; ks++)
        bK[ks] = *(const bf16x8*)&Ks[buf][ks * 16 + l15][(((4 * c + lg) ^ (l15 & 7)) * 8)];
#pragma unroll
      for (int ks = 0; ks < 4; ks++)
        S[ks] = __builtin_amdgcn_mfma_f32_16x16x32_bf16(aQ[c], bK[ks], S[ks], 0, 0, 0);
    }

    // ---- fixed-max softmax: P = exp(S*scale - 32), masked -> 0 ----
    {
      const int qrow0 = q0 + w * 16 + 4 * lg;
#pragma unroll
      for (int ks = 0; ks < 4; ks++) {
        const int kg = k0 + ks * 16 + l15;
#pragma unroll
        for (int rr = 0; rr < 4; rr++) {
          const float e = __expf(fmaf(S[ks][rr], scale, -32.f));
          S[ks][rr] = (kg > qrow0 + rr) ? 0.f : e;
        }
      }
#pragma unroll
      for (int ks = 0; ks < 4; ks++)
#pragma unroll
        for (int rr = 0; rr < 4; rr++) {
          const int row = 4 * lg + rr;
          const int G = (2 * ks + (l15 >> 3)) ^ (row & 7);
          Ps[w][row][G * 8 + (l15 & 7)] = f2bf(S[ks][rr]);
        }
    }

    // ---- PV + lsum ----
#pragma unroll
    for (int kk = 0; kk < 2; kk++) {
      const int pg = ((4 * kk + lg) ^ (l15 & 7)) * 8;
      bf16x8 pF = *(const bf16x8*)&Ps[w][l15][pg];
#pragma unroll
      for (int dt = 0; dt < 8; dt++) {
        bf16x8 vF = *(const bf16x8*)&Vs[buf][dt * 16 + l15][pg];
        Y[dt] = __builtin_amdgcn_mfma_f32_16x16x32_bf16(pF, vF, Y[dt], 0, 0, 0);
      }
      LS = __builtin_amdgcn_mfma_f32_16x16x32_bf16(pF, ones, LS, 0, 0, 0);
    }
    asm volatile("" ::: "memory");
    __builtin_amdgcn_s_barrier();
    asm volatile("" ::: "memory");
  }

  // ---- normalize + write ----
  float inv[4];
#pragma unroll
  for (int rr = 0; rr < 4; rr++) inv[rr] = 1.0f / LS[rr];
#pragma unroll
  for (int dt = 0; dt < 8; dt++)
#pragma unroll
    for (int rr = 0; rr < 4; rr++)
      y[(long)(q0 + w * 16 + 4 * lg + rr) * 4096 + h * 128 + dt * 16 + l15] =
          f2bf(Y[dt][rr] * inv[rr]);
}

// ---------------- host ----------------
extern "C" void kernel_launch(void* const* d_in, const int* in_sizes, int n_in,
                              void* d_out, int out_size, void* d_ws, size_t ws_size,
                              hipStream_t stream) {
  const float* x    = (const float*)d_in[0];
  const float* Wq   = (const float*)d_in[1];
  const float* Wk   = (const float*)d_in[2];
  const float* Wv   = (const float*)d_in[3];
  const float* Wo   = (const float*)d_in[4];
  const float* Wm   = (const float*)d_in[5];
  const float* beta = (const float*)d_in[6];
  const float* fc   = (const float*)d_in[7];
  const float* fs   = (const float*)d_in[8];
  float* out = (float*)d_out;

  const long TC = 2048L * 4096L;     // 8,388,608
  const long WSZ = 8L * 512 * 512;   // 2,097,152
  u16* ws  = (u16*)d_ws;
  u16* xb  = ws;                     // [T][C] bf16 x           (later reused as y_att)
  u16* wt  = ws + TC;                // Wq,Wk,Wv,Wo transposed bf16
  u16* wmt = wt + 4 * WSZ;           // mixer W transposed*beta
  u16* g3  = wmt + 131072L;          // scratch (ymix)
  u16* r3  = g3 + 3 * TC;            // qR, kR [H][T][D]; vT [H][D][T]
  u16* yatt = xb;
  u16* ymix = g3;

  conv_f32_bf16_vec<<<TC / 4 / 256, 256, 0, stream>>>(x, xb);
  transpose_w4<<<dim3(8, 8, 32), 256, 0, stream>>>(Wq, Wk, Wv, Wo, wt, WSZ);
  transpose_wm<<<512, 256, 0, stream>>>(Wm, beta, wmt);

  // fused q,k,v GEMM: single-buffer 40KB, 4 blocks/CU; rope + v-transpose fused
  oct_gemmQKV3<<<dim3(64, 16), 256, 0, stream>>>(
      xb, wt, r3, r3 + TC, r3 + 2 * TC, fc, fs, WSZ);

  attn5<<<1024, 256, 0, stream>>>(r3, r3 + TC, r3 + 2 * TC, yatt);

  // mixer: BS=128, K=1024, N-slab 1024 per group, A col offset 1024 per group
  oct_gemm128<0><<<dim3(32, 16), 256, 0, stream>>>(
      yatt, wmt, (void*)ymix,
      1024, 4096, 4096, 10, 7, 0L, 1024L, 1024L);

  // final oct_linear with Wo -> f32 out
  oct_gemm128<2><<<dim3(32, 16), 256, 0, stream>>>(
      ymix, wt + 3 * WSZ, (void*)out,
      4096, 4096, 4096, 12, 9, 0L, 0L, 0L);
}

// Round 14
// 443.082 us; speedup vs baseline: 1.4019x; 1.4019x over previous
//
#include <hip/hip_runtime.h>

typedef float f32x4 __attribute__((ext_vector_type(4)));
typedef __bf16 bf16x8 __attribute__((ext_vector_type(8)));
typedef unsigned short u16;
typedef u16 u16x8 __attribute__((ext_vector_type(8)));

// Octonion sign table from Cayley-Dickson (levels=3): OSGN[i][j] = sign of e_i*e_j.
__constant__ float c_osgn[64] = {
  1, 1, 1, 1, 1, 1, 1, 1,
  1,-1, 1,-1, 1,-1,-1, 1,
  1,-1,-1, 1, 1, 1,-1,-1,
  1, 1,-1,-1, 1,-1, 1,-1,
  1,-1,-1,-1,-1, 1, 1, 1,
  1, 1,-1, 1,-1,-1,-1, 1,
  1, 1, 1,-1,-1, 1,-1,-1,
  1,-1, 1, 1,-1,-1, 1,-1
};

__device__ __forceinline__ u16 f2bf(float f) {
  union { float f; unsigned u; } v; v.f = f;
  unsigned u = v.u;
  return (u16)((u + 0x7fffu + ((u >> 16) & 1u)) >> 16);
}
__device__ __forceinline__ float bf2f(u16 h) {
  union { unsigned u; float f; } v; v.u = ((unsigned)h) << 16;
  return v.f;
}

typedef const __attribute__((address_space(1))) void* as1cv;
typedef __attribute__((address_space(3))) void* as3v;
__device__ __forceinline__ void load16_lds(const void* g, void* l) {
  __builtin_amdgcn_global_load_lds((as1cv)g, (as3v)l, 16, 0, 0);
}

// ---------------- converts ----------------
__global__ void conv_f32_bf16_vec(const float* __restrict__ src, u16* __restrict__ dst) {
  int i = blockIdx.x * 256 + threadIdx.x;       // over n/4 exact
  float4 v = ((const float4*)src)[i];
  ushort4 o; o.x = f2bf(v.x); o.y = f2bf(v.y); o.z = f2bf(v.z); o.w = f2bf(v.w);
  ((ushort4*)dst)[i] = o;
}

// 4 weight tensors W[w][p][q] (f32) -> Wt[w][q][p] (bf16), LDS-tiled, one launch.
__global__ __launch_bounds__(256) void transpose_w4(
    const float* __restrict__ Wq, const float* __restrict__ Wk,
    const float* __restrict__ Wv, const float* __restrict__ Wo,
    u16* __restrict__ WtB, long wsz) {
  __shared__ float t[64][65];
  const int zw = blockIdx.z;
  const int wsel = zw >> 3, w = zw & 7;
  const float* W = (wsel == 0) ? Wq : (wsel == 1) ? Wk : (wsel == 2) ? Wv : Wo;
  u16* Wt = WtB + wsel * wsz;
  const int p0 = blockIdx.y * 64, q0 = blockIdx.x * 64;
  const float* src = W + ((long)w * 512 + p0) * 512 + q0;
  const int tid = threadIdx.x;
  const int r = tid >> 2, c0 = (tid & 3) * 16;
#pragma unroll
  for (int j = 0; j < 4; j++) {
    float4 v = *(const float4*)(src + (long)r * 512 + c0 + j * 4);
    t[r][c0 + j * 4 + 0] = v.x; t[r][c0 + j * 4 + 1] = v.y;
    t[r][c0 + j * 4 + 2] = v.z; t[r][c0 + j * 4 + 3] = v.w;
  }
  __syncthreads();
  u16* dst = Wt + ((long)w * 512 + q0) * 512 + p0;
#pragma unroll
  for (int j = 0; j < 2; j++) {
    u16x8 o;
#pragma unroll
    for (int k = 0; k < 8; k++) o[k] = f2bf(t[c0 + j * 8 + k][r]);
    *(u16x8*)(dst + (long)r * 512 + c0 + j * 8) = o;
  }
}

// mixer_W[w][d][e] -> Wmt[w][e][d] * beta[e]
__global__ void transpose_wm(const float* __restrict__ W, const float* __restrict__ beta,
                             u16* __restrict__ Wt) {
  int idx = blockIdx.x * 256 + threadIdx.x;     // 8*128*128 exact
  int w = idx >> 14, rem = idx & 16383;
  int e = rem >> 7, d = rem & 127;
  Wt[(w << 14) + (e << 7) + d] = f2bf(W[(w << 14) + (d << 7) + e] * beta[e]);
}

// ---------------- fused QKV oct GEMM v3b: 128x64 tile, z-fused, single-buffer, 3 blocks/CU ----
// BM=128, BN=64, BK=64. 4 waves (2M x 2N), wave tile 64x32, 48 MFMA/wave/step (3 z).
// LDS 40 KB -> 3 blocks/CU fit LDS-wise (120 KB); launch_bounds(256,3) keeps VGPR cap
// at ~168 so the 96-VGPR accumulator does NOT spill (r13's (256,4) forced a spill:
// VGPR=64, FETCH 1.35 GB, 2x slowdown). m97 schedule: stage -> sync -> compute -> sync.
__global__ __launch_bounds__(256, 3) void oct_gemmQKV3(
    const u16* __restrict__ A, const u16* __restrict__ WtB,
    u16* __restrict__ out0, u16* __restrict__ out1, u16* __restrict__ out2,
    const float* __restrict__ fc, const float* __restrict__ fs, long wsz)
{
  __shared__ u16 smem[20480];   // As: [0..8191]; Bs z: 8192 + z*4096

  const int nwg = gridDim.x * gridDim.y;            // 1024
  const int lin = blockIdx.y * gridDim.x + blockIdx.x;
  const int swz = (lin & 7) * (nwg >> 3) + (lin >> 3);
  const int bx = swz % gridDim.x, by = swz / gridDim.x;

  const int np = bx * 64;             // 0..4032
  const int bi = np >> 9;
  const int nsub = np & 511;
  const int bm = by * 128;
  const int h = np >> 7;
  const int dbase = np & 64;          // 0 or 64: d-offset within head

  const int tid = threadIdx.x;
  const int lane = tid & 63, w = tid >> 6;
  const int l15 = lane & 15, lg = lane >> 4;
  const int wm = w >> 1, wn = w & 1;  // wave tile: rows wm*64, cols wn*32
  const int srow = lane >> 3;
  const int sgr  = (lane & 7) ^ srow;

  f32x4 acc[3][4][2];
#pragma unroll
  for (int z = 0; z < 3; z++)
#pragma unroll
    for (int a = 0; a < 4; a++)
#pragma unroll
      for (int b = 0; b < 2; b++) acc[z][a][b] = f32x4{0.f, 0.f, 0.f, 0.f};

  for (int t = 0; t < 64; ++t) {
    const int k0 = t << 6;
    const int bj = t >> 3;
    const int widx = bi ^ bj;
    const unsigned xm = (c_osgn[bj * 8 + widx] < 0.f) ? 0x80008000u : 0u;
    const long woff = (long)widx * 262144 + (k0 & 511);

    // stage: A 4 + B 3z x 2 DMA/thread
#pragma unroll
    for (int i = 0; i < 4; i++) {
      const int r = (w * 4 + i) * 8;
      load16_lds(A + (long)(bm + r + srow) * 4096 + k0 + sgr * 8,
                 (void*)(smem + r * 64));
    }
#pragma unroll
    for (int z = 0; z < 3; z++) {
      const u16* Wsrc = WtB + (long)z * wsz + woff;
#pragma unroll
      for (int i = 0; i < 2; i++) {
        const int r = (w * 2 + i) * 8;
        load16_lds(Wsrc + (long)(nsub + r + srow) * 512 + sgr * 8,
                   (void*)(smem + 8192 + z * 4096 + r * 64));
      }
    }
    __syncthreads();

#pragma unroll
    for (int kk = 0; kk < 2; kk++) {
      const int gsw = ((4 * kk + lg) ^ (l15 & 7)) * 8;
      uint4 a4[4];
#pragma unroll
      for (int mt = 0; mt < 4; mt++)
        a4[mt] = *(const uint4*)(smem + (wm * 64 + mt * 16 + l15) * 64 + gsw);
      if (xm) {
#pragma unroll
        for (int mt = 0; mt < 4; mt++) {
          a4[mt].x ^= xm; a4[mt].y ^= xm; a4[mt].z ^= xm; a4[mt].w ^= xm;
        }
      }
#pragma unroll
      for (int z = 0; z < 3; z++) {
        bf16x8 bF[2];
#pragma unroll
        for (int nt = 0; nt < 2; nt++)
          bF[nt] = *(const bf16x8*)(smem + 8192 + z * 4096 +
                                    (wn * 32 + nt * 16 + l15) * 64 + gsw);
#pragma unroll
        for (int mt = 0; mt < 4; mt++)
#pragma unroll
          for (int nt = 0; nt < 2; nt++)
            acc[z][mt][nt] = __builtin_amdgcn_mfma_f32_16x16x32_bf16(
                *(const bf16x8*)&a4[mt], bF[nt], acc[z][mt][nt], 0, 0, 0);
      }
    }
    __syncthreads();
  }

  // ---- epilogue: rope q, rope k ----
#pragma unroll
  for (int z = 0; z < 2; z++) {
    u16* dq = (z == 0) ? out0 : out1;
#pragma unroll
    for (int mt = 0; mt < 4; mt++)
#pragma unroll
      for (int nt = 0; nt < 2; nt++) {
        const int d = dbase + wn * 32 + nt * 16 + l15;
        const int p = d >> 1;
        const bool ev = (l15 & 1) == 0;
#pragma unroll
        for (int j = 0; j < 4; j++) {
          const int trow = bm + wm * 64 + mt * 16 + 4 * lg + j;
          const float v = acc[z][mt][nt][j];
          const float sh = __shfl_xor(v, 1);
          const float c = fc[trow * 64 + p];
          const float s = fs[trow * 64 + p];
          const float o = ev ? (v * c - sh * s) : (sh * s + v * c);
          dq[((long)h * 2048 + trow) * 128 + d] = f2bf(o);
        }
      }
  }

  // ---- epilogue: v transposed [H][D][T] via LDS bounce [64][136] ----
#pragma unroll
  for (int mt = 0; mt < 4; mt++)
#pragma unroll
    for (int nt = 0; nt < 2; nt++)
#pragma unroll
      for (int j = 0; j < 4; j++)
        smem[(wn * 32 + nt * 16 + l15) * 136 + wm * 64 + mt * 16 + 4 * lg + j] =
            f2bf(acc[2][mt][nt][j]);
  __syncthreads();
  {
    const int dl = tid >> 2;          // 0..63
    const int tc = (tid & 3) * 32;    // 0,32,64,96
#pragma unroll
    for (int q = 0; q < 4; q++) {
      u16x8 o = *(const u16x8*)(smem + dl * 136 + tc + q * 8);
      *(u16x8*)(out2 + ((long)h * 128 + dbase + dl) * 2048 + bm + tc + q * 8) = o;
    }
  }
}

// ---------------- oct GEMM, m97 structure: 128x128, BK=64, single-buffer ----------------
template <int MODE>
__global__ __launch_bounds__(256, 3) void oct_gemm128(
    const u16* __restrict__ A, const u16* __restrict__ WtB,
    void* __restrict__ out0,
    int K, int lda, int ldo,
    int slab_shift, int bs_shift, long wslab, long oslab, long acolslab)
{
  __shared__ u16 smem[16384];
  const int NT = K >> 6;
  const int BS = 1 << bs_shift;
  const long wblk = (long)BS * BS;

  const int nwg = gridDim.x * gridDim.y;
  const int lin = blockIdx.y * gridDim.x + blockIdx.x;
  const int swz = (lin & 7) * (nwg >> 3) + (lin >> 3);
  const int bx = swz % gridDim.x, by = swz / gridDim.x;

  const int nglob = bx * 128;
  const int z = nglob >> slab_shift;
  const int np = nglob & ((1 << slab_shift) - 1);
  const int bi = np >> bs_shift;
  const int nsub = np & (BS - 1);
  const int bm = by * 128;
  const u16* Wt = WtB + (long)z * wslab;
  const long acol0 = (long)z * acolslab;

  const int tid = threadIdx.x;
  const int lane = tid & 63, w = tid >> 6;
  const int l15 = lane & 15, lg = lane >> 4;
  const int wm = w >> 1, wn = w & 1;
  const int srow = lane >> 3;
  const int sgr  = (lane & 7) ^ srow;

  f32x4 acc[4][4];
#pragma unroll
  for (int a = 0; a < 4; a++)
#pragma unroll
    for (int b = 0; b < 4; b++) acc[a][b] = f32x4{0.f, 0.f, 0.f, 0.f};

  for (int t = 0; t < NT; ++t) {
    const int k0 = t << 6;
    const int bj = k0 >> bs_shift;
    const int widx = bi ^ bj;
    const unsigned xm = (c_osgn[bj * 8 + widx] < 0.f) ? 0x80008000u : 0u;
    const u16* Wsrc = Wt + (long)widx * wblk + (k0 & (BS - 1));

#pragma unroll
    for (int i = 0; i < 4; i++) {
      const int r = (w * 4 + i) * 8;
      load16_lds(A + (long)(bm + r + srow) * lda + acol0 + k0 + sgr * 8,
                 (void*)(smem + r * 64));
    }
#pragma unroll
    for (int i = 0; i < 4; i++) {
      const int r = (w * 4 + i) * 8;
      load16_lds(Wsrc + (long)(nsub + r + srow) * BS + sgr * 8,
                 (void*)(smem + 8192 + r * 64));
    }
    __syncthreads();

#pragma unroll
    for (int kk = 0; kk < 64; kk += 32) {
      const int gsw = (((kk >> 3) + lg) ^ (l15 & 7)) * 8;
      uint4 a4[4];
      bf16x8 bF[4];
#pragma unroll
      for (int mt = 0; mt < 4; mt++)
        a4[mt] = *(const uint4*)(smem + (wm * 64 + mt * 16 + l15) * 64 + gsw);
      if (xm) {
#pragma unroll
        for (int mt = 0; mt < 4; mt++) {
          a4[mt].x ^= xm; a4[mt].y ^= xm; a4[mt].z ^= xm; a4[mt].w ^= xm;
        }
      }
#pragma unroll
      for (int nt = 0; nt < 4; nt++)
        bF[nt] = *(const bf16x8*)(smem + 8192 + (wn * 64 + nt * 16 + l15) * 64 + gsw);
#pragma unroll
      for (int mt = 0; mt < 4; mt++)
#pragma unroll
        for (int nt = 0; nt < 4; nt++)
          acc[mt][nt] = __builtin_amdgcn_mfma_f32_16x16x32_bf16(
              *(const bf16x8*)&a4[mt], bF[nt], acc[mt][nt], 0, 0, 0);
    }
    __syncthreads();
  }

#pragma unroll
  for (int mt = 0; mt < 4; mt++)
#pragma unroll
    for (int nt = 0; nt < 4; nt++)
#pragma unroll
      for (int j = 0; j < 4; j++) {
        const int row = bm + wm * 64 + mt * 16 + 4 * lg + j;
        const int col = np + wn * 64 + nt * 16 + l15;
        const float v = acc[mt][nt][j];
        if constexpr (MODE == 0)
          ((u16*)out0)[(long)z * oslab + (long)row * ldo + col] = f2bf(v);
        else
          ((float*)out0)[(long)row * ldo + col] = v;
      }
}

// ---------------- flash attention v5: fixed-max softmax + lsum via ones-MFMA ----------------
__global__ __launch_bounds__(256, 2) void attn5(
    const u16* __restrict__ qR, const u16* __restrict__ kR,
    const u16* __restrict__ vT, u16* __restrict__ y)
{
  const int bid = blockIdx.x;
  const int h = bid & 31;
  const int qb = 31 - (bid >> 5);        // longest blocks dispatched first
  const int q0 = qb * 64;

  const int tid = threadIdx.x;
  const int lane = tid & 63, w = tid >> 6;
  const int l15 = lane & 15, lg = lane >> 4;

  __shared__ u16 Ks[2][64][128];
  __shared__ u16 Vs[2][128][64];
  __shared__ u16 Ps[4][16][64];

  auto stageK = [&](int kb, int buf) {
    const long kbase = (long)h * 2048 + (long)kb * 64;
#pragma unroll
    for (int i = 0; i < 4; i++) {
      const int j = w * 4 + i;
      const int row = j * 4 + (lane >> 4);
      const int sg = (lane & 15) ^ (row & 7);
      load16_lds(kR + (kbase + row) * 128 + sg * 8, (void*)&Ks[buf][j * 4][0]);
    }
  };
  auto stageV = [&](int kb, int buf) {
    const long vbase = (long)h * 128 * 2048 + (long)kb * 64;
#pragma unroll
    for (int i = 0; i < 4; i++) {
      const int j = w * 4 + i;
      const int row = j * 8 + (lane >> 3);
      const int sg = (lane & 7) ^ (row & 7);
      load16_lds(vT + vbase + (long)row * 2048 + sg * 8, (void*)&Vs[buf][j * 8][0]);
    }
  };

  stageK(0, 0);
  stageV(0, 0);

  bf16x8 aQ[4];
  {
    const long qbase = ((long)h * 2048 + q0 + w * 16 + l15) * 128;
#pragma unroll
    for (int c = 0; c < 4; c++)
      aQ[c] = *(const bf16x8*)(qR + qbase + 32 * c + 8 * lg);
  }

  bf16x8 ones;
#pragma unroll
  for (int j = 0; j < 8; j++) ones[j] = (__bf16)1.0f;

  f32x4 Y[8], LS;
#pragma unroll
  for (int dt = 0; dt < 8; dt++) Y[dt] = f32x4{0.f, 0.f, 0.f, 0.f};
  LS = f32x4{0.f, 0.f, 0.f, 0.f};

  const float scale = 0.08838834764831845f;   // 1/sqrt(128)
  const int nkb = qb + 1;

  for (int kb = 0; kb < nkb; kb++) {
    const int buf = kb & 1;
    const int k0 = kb * 64;
    if (kb + 1 < nkb) { stageK(kb + 1, buf ^ 1); stageV(kb + 1, buf ^ 1); }
    if (kb + 1 < nkb) asm volatile("s_waitcnt vmcnt(8)" ::: "memory");
    else              asm volatile("s_waitcnt vmcnt(0)" ::: "memory");
    __builtin_amdgcn_s_barrier();
    asm volatile("" ::: "memory");

    // ---- QK^T ----
    f32x4 S[4];
#pragma unroll
    for (int ks = 0; ks < 4; ks++) S[ks] = f32x4{0.f, 0.f, 0.f, 0.f};
#pragma unroll
    for (int c = 0; c < 4; c++) {
      bf16x8 bK[4];
#pragma unroll
      for (int ks = 0; ks < 4; ks++)
        bK[ks] = *(const bf16x8*)&Ks[buf][ks * 16 + l15][(((4 * c + lg) ^ (l15 & 7)) * 8)];
#pragma unroll
      for (int ks = 0; ks < 4; ks++)
        S[ks] = __builtin_amdgcn_mfma_f32_16x16x32_bf16(aQ[c], bK[ks], S[ks], 0, 0, 0);
    }

    // ---- fixed-max softmax: P = exp(S*scale - 32), masked -> 0 ----
    {
      const int qrow0 = q0 + w * 16 + 4 * lg;
#pragma unroll
      for (int ks = 0; ks < 4; ks++) {
        const int kg = k0 + ks * 16 + l15;
#pragma unroll
        for (int rr = 0; rr < 4; rr++) {
          const float e = __expf(fmaf(S[ks][rr], scale, -32.f));
          S[ks][rr] = (kg > qrow0 + rr) ? 0.f : e;
        }
      }
#pragma unroll
      for (int ks = 0; ks < 4; ks++)
#pragma unroll
        for (int rr = 0; rr < 4; rr++) {
          const int row = 4 * lg + rr;
          const int G = (2 * ks + (l15 >> 3)) ^ (row & 7);
          Ps[w][row][G * 8 + (l15 & 7)] = f2bf(S[ks][rr]);
        }
    }

    // ---- PV + lsum ----
#pragma unroll
    for (int kk = 0; kk < 2; kk++) {
      const int pg = ((4 * kk + lg) ^ (l15 & 7)) * 8;
      bf16x8 pF = *(const bf16x8*)&Ps[w][l15][pg];
#pragma unroll
      for (int dt = 0; dt < 8; dt++) {
        bf16x8 vF = *(const bf16x8*)&Vs[buf][dt * 16 + l15][pg];
        Y[dt] = __builtin_amdgcn_mfma_f32_16x16x32_bf16(pF, vF, Y[dt], 0, 0, 0);
      }
      LS = __builtin_amdgcn_mfma_f32_16x16x32_bf16(pF, ones, LS, 0, 0, 0);
    }
    asm volatile("" ::: "memory");
    __builtin_amdgcn_s_barrier();
    asm volatile("" ::: "memory");
  }

  // ---- normalize + write ----
  float inv[4];
#pragma unroll
  for (int rr = 0; rr < 4; rr++) inv[rr] = 1.0f / LS[rr];
#pragma unroll
  for (int dt = 0; dt < 8; dt++)
#pragma unroll
    for (int rr = 0; rr < 4; rr++)
      y[(long)(q0 + w * 16 + 4 * lg + rr) * 4096 + h * 128 + dt * 16 + l15] =
          f2bf(Y[dt][rr] * inv[rr]);
}

// ---------------- host ----------------
extern "C" void kernel_launch(void* const* d_in, const int* in_sizes, int n_in,
                              void* d_out, int out_size, void* d_ws, size_t ws_size,
                              hipStream_t stream) {
  const float* x    = (const float*)d_in[0];
  const float* Wq   = (const float*)d_in[1];
  const float* Wk   = (const float*)d_in[2];
  const float* Wv   = (const float*)d_in[3];
  const float* Wo   = (const float*)d_in[4];
  const float* Wm   = (const float*)d_in[5];
  const float* beta = (const float*)d_in[6];
  const float* fc   = (const float*)d_in[7];
  const float* fs   = (const float*)d_in[8];
  float* out = (float*)d_out;

  const long TC = 2048L * 4096L;     // 8,388,608
  const long WSZ = 8L * 512 * 512;   // 2,097,152
  u16* ws  = (u16*)d_ws;
  u16* xb  = ws;                     // [T][C] bf16 x           (later reused as y_att)
  u16* wt  = ws + TC;                // Wq,Wk,Wv,Wo transposed bf16
  u16* wmt = wt + 4 * WSZ;           // mixer W transposed*beta
  u16* g3  = wmt + 131072L;          // scratch (ymix)
  u16* r3  = g3 + 3 * TC;            // qR, kR [H][T][D]; vT [H][D][T]
  u16* yatt = xb;
  u16* ymix = g3;

  conv_f32_bf16_vec<<<TC / 4 / 256, 256, 0, stream>>>(x, xb);
  transpose_w4<<<dim3(8, 8, 32), 256, 0, stream>>>(Wq, Wk, Wv, Wo, wt, WSZ);
  transpose_wm<<<512, 256, 0, stream>>>(Wm, beta, wmt);

  // fused q,k,v GEMM: single-buffer 40KB, 3 blocks/CU (no VGPR spill); rope + v-T fused
  oct_gemmQKV3<<<dim3(64, 16), 256, 0, stream>>>(
      xb, wt, r3, r3 + TC, r3 + 2 * TC, fc, fs, WSZ);

  attn5<<<1024, 256, 0, stream>>>(r3, r3 + TC, r3 + 2 * TC, yatt);

  // mixer: BS=128, K=1024, N-slab 1024 per group, A col offset 1024 per group
  oct_gemm128<0><<<dim3(32, 16), 256, 0, stream>>>(
      yatt, wmt, (void*)ymix,
      1024, 4096, 4096, 10, 7, 0L, 1024L, 1024L);

  // final oct_linear with Wo -> f32 out
  oct_gemm128<2><<<dim3(32, 16), 256, 0, stream>>>(
      ymix, wt + 3 * WSZ, (void*)out,
      4096, 4096, 4096, 12, 9, 0L, 0L, 0L);
}

// Round 15
// 396.435 us; speedup vs baseline: 1.5668x; 1.1177x over previous
//
#include <hip/hip_runtime.h>

typedef float f32x4 __attribute__((ext_vector_type(4)));
typedef __bf16 bf16x8 __attribute__((ext_vector_type(8)));
typedef unsigned short u16;
typedef u16 u16x8 __attribute__((ext_vector_type(8)));

// Octonion sign table from Cayley-Dickson (levels=3): OSGN[i][j] = sign of e_i*e_j.
__constant__ float c_osgn[64] = {
  1, 1, 1, 1, 1, 1, 1, 1,
  1,-1, 1,-1, 1,-1,-1, 1,
  1,-1,-1, 1, 1, 1,-1,-1,
  1, 1,-1,-1, 1,-1, 1,-1,
  1,-1,-1,-1,-1, 1, 1, 1,
  1, 1,-1, 1,-1,-1,-1, 1,
  1, 1, 1,-1,-1, 1,-1,-1,
  1,-1, 1, 1,-1,-1, 1,-1
};

__device__ __forceinline__ u16 f2bf(float f) {
  union { float f; unsigned u; } v; v.f = f;
  unsigned u = v.u;
  return (u16)((u + 0x7fffu + ((u >> 16) & 1u)) >> 16);
}
__device__ __forceinline__ float bf2f(u16 h) {
  union { unsigned u; float f; } v; v.u = ((unsigned)h) << 16;
  return v.f;
}

typedef const __attribute__((address_space(1))) void* as1cv;
typedef __attribute__((address_space(3))) void* as3v;
__device__ __forceinline__ void load16_lds(const void* g, void* l) {
  __builtin_amdgcn_global_load_lds((as1cv)g, (as3v)l, 16, 0, 0);
}

// ---------------- converts ----------------
__global__ void conv_f32_bf16_vec(const float* __restrict__ src, u16* __restrict__ dst) {
  int i = blockIdx.x * 256 + threadIdx.x;       // over n/4 exact
  float4 v = ((const float4*)src)[i];
  ushort4 o; o.x = f2bf(v.x); o.y = f2bf(v.y); o.z = f2bf(v.z); o.w = f2bf(v.w);
  ((ushort4*)dst)[i] = o;
}

// 4 weight tensors W[w][p][q] (f32) -> Wt[w][q][p] (bf16), LDS-tiled, one launch.
__global__ __launch_bounds__(256) void transpose_w4(
    const float* __restrict__ Wq, const float* __restrict__ Wk,
    const float* __restrict__ Wv, const float* __restrict__ Wo,
    u16* __restrict__ WtB, long wsz) {
  __shared__ float t[64][65];
  const int zw = blockIdx.z;
  const int wsel = zw >> 3, w = zw & 7;
  const float* W = (wsel == 0) ? Wq : (wsel == 1) ? Wk : (wsel == 2) ? Wv : Wo;
  u16* Wt = WtB + wsel * wsz;
  const int p0 = blockIdx.y * 64, q0 = blockIdx.x * 64;
  const float* src = W + ((long)w * 512 + p0) * 512 + q0;
  const int tid = threadIdx.x;
  const int r = tid >> 2, c0 = (tid & 3) * 16;
#pragma unroll
  for (int j = 0; j < 4; j++) {
    float4 v = *(const float4*)(src + (long)r * 512 + c0 + j * 4);
    t[r][c0 + j * 4 + 0] = v.x; t[r][c0 + j * 4 + 1] = v.y;
    t[r][c0 + j * 4 + 2] = v.z; t[r][c0 + j * 4 + 3] = v.w;
  }
  __syncthreads();
  u16* dst = Wt + ((long)w * 512 + q0) * 512 + p0;
#pragma unroll
  for (int j = 0; j < 2; j++) {
    u16x8 o;
#pragma unroll
    for (int k = 0; k < 8; k++) o[k] = f2bf(t[c0 + j * 8 + k][r]);
    *(u16x8*)(dst + (long)r * 512 + c0 + j * 8) = o;
  }
}

// mixer_W[w][d][e] -> Wmt[w][e][d] * beta[e]
__global__ void transpose_wm(const float* __restrict__ W, const float* __restrict__ beta,
                             u16* __restrict__ Wt) {
  int idx = blockIdx.x * 256 + threadIdx.x;     // 8*128*128 exact
  int w = idx >> 14, rem = idx & 16383;
  int e = rem >> 7, d = rem & 127;
  Wt[(w << 14) + (e << 7) + d] = f2bf(W[(w << 14) + (d << 7) + e] * beta[e]);
}

// ---------------- fused QKV oct GEMM: 128x128 tile, z-fused (q,k,v share A) ----------------
// Per K-step: stage A once + 3 B-tiles, 96 MFMA per barrier pair. LDS 64 KB
// single-buffered -> 2 blocks/CU. Sign XOR on A once. Epilogue: rope(q)->out0,
// rope(k)->out1, v transposed [H][D][T]->out2 (LDS bounce, stride 152).
__global__ __launch_bounds__(256, 2) void oct_gemmQKV(
    const u16* __restrict__ A, const u16* __restrict__ WtB,
    u16* __restrict__ out0, u16* __restrict__ out1, u16* __restrict__ out2,
    const float* __restrict__ fc, const float* __restrict__ fs, long wsz)
{
  __shared__ u16 smem[32768];   // As [0..8191]; Bs z at 8192*(1+z)

  const int nwg = gridDim.x * gridDim.y;            // 512
  const int lin = blockIdx.y * gridDim.x + blockIdx.x;
  const int swz = (lin & 7) * (nwg >> 3) + (lin >> 3);
  const int bx = swz % gridDim.x, by = swz / gridDim.x;

  const int np = bx * 128;            // 0..4095
  const int bi = np >> 9;
  const int nsub = np & 511;
  const int bm = by * 128;
  const int h = np >> 7;

  const int tid = threadIdx.x;
  const int lane = tid & 63, w = tid >> 6;
  const int l15 = lane & 15, lg = lane >> 4;
  const int wm = w >> 1, wn = w & 1;
  const int srow = lane >> 3;
  const int sgr  = (lane & 7) ^ srow;

  f32x4 acc[3][4][4];
#pragma unroll
  for (int z = 0; z < 3; z++)
#pragma unroll
    for (int a = 0; a < 4; a++)
#pragma unroll
      for (int b = 0; b < 4; b++) acc[z][a][b] = f32x4{0.f, 0.f, 0.f, 0.f};

  for (int t = 0; t < 64; ++t) {
    const int k0 = t << 6;
    const int bj = t >> 3;
    const int widx = bi ^ bj;
    const unsigned xm = (c_osgn[bj * 8 + widx] < 0.f) ? 0x80008000u : 0u;
    const long woff = (long)widx * 262144 + (k0 & 511);

#pragma unroll
    for (int i = 0; i < 4; i++) {
      const int r = (w * 4 + i) * 8;
      load16_lds(A + (long)(bm + r + srow) * 4096 + k0 + sgr * 8,
                 (void*)(smem + r * 64));
    }
#pragma unroll
    for (int z = 0; z < 3; z++) {
      const u16* Wsrc = WtB + (long)z * wsz + woff;
#pragma unroll
      for (int i = 0; i < 4; i++) {
        const int r = (w * 4 + i) * 8;
        load16_lds(Wsrc + (long)(nsub + r + srow) * 512 + sgr * 8,
                   (void*)(smem + 8192 * (1 + z) + r * 64));
      }
    }
    __syncthreads();

#pragma unroll
    for (int kk = 0; kk < 64; kk += 32) {
      const int gsw = (((kk >> 3) + lg) ^ (l15 & 7)) * 8;
      uint4 a4[4];
#pragma unroll
      for (int mt = 0; mt < 4; mt++)
        a4[mt] = *(const uint4*)(smem + (wm * 64 + mt * 16 + l15) * 64 + gsw);
      if (xm) {
#pragma unroll
        for (int mt = 0; mt < 4; mt++) {
          a4[mt].x ^= xm; a4[mt].y ^= xm; a4[mt].z ^= xm; a4[mt].w ^= xm;
        }
      }
#pragma unroll
      for (int z = 0; z < 3; z++) {
        bf16x8 bF[4];
#pragma unroll
        for (int nt = 0; nt < 4; nt++)
          bF[nt] = *(const bf16x8*)(smem + 8192 * (1 + z) +
                                    (wn * 64 + nt * 16 + l15) * 64 + gsw);
#pragma unroll
        for (int mt = 0; mt < 4; mt++)
#pragma unroll
          for (int nt = 0; nt < 4; nt++)
            acc[z][mt][nt] = __builtin_amdgcn_mfma_f32_16x16x32_bf16(
                *(const bf16x8*)&a4[mt], bF[nt], acc[z][mt][nt], 0, 0, 0);
      }
    }
    __syncthreads();
  }

  // ---- epilogue: rope q, rope k ----
#pragma unroll
  for (int z = 0; z < 2; z++) {
    u16* dq = (z == 0) ? out0 : out1;
#pragma unroll
    for (int mt = 0; mt < 4; mt++)
#pragma unroll
      for (int nt = 0; nt < 4; nt++) {
        const int d = wn * 64 + nt * 16 + l15;
        const int p = d >> 1;
        const bool ev = (l15 & 1) == 0;
#pragma unroll
        for (int j = 0; j < 4; j++) {
          const int trow = bm + wm * 64 + mt * 16 + 4 * lg + j;
          const float v = acc[z][mt][nt][j];
          const float sh = __shfl_xor(v, 1);
          const float c = fc[trow * 64 + p];
          const float s = fs[trow * 64 + p];
          const float o = ev ? (v * c - sh * s) : (sh * s + v * c);
          dq[((long)h * 2048 + trow) * 128 + d] = f2bf(o);
        }
      }
  }

  // ---- epilogue: v transposed via LDS bounce (stride 152 u16 ≡ 12 banks, 2-way free) ----
#pragma unroll
  for (int dh = 0; dh < 2; ++dh) {
    __syncthreads();
    if (wn == dh) {
#pragma unroll
      for (int mt = 0; mt < 4; mt++)
#pragma unroll
        for (int nt = 0; nt < 4; nt++)
#pragma unroll
          for (int j = 0; j < 4; j++)
            smem[(nt * 16 + l15) * 152 + wm * 64 + mt * 16 + 4 * lg + j] =
                f2bf(acc[2][mt][nt][j]);
    }
    __syncthreads();
#pragma unroll
    for (int p = 0; p < 4; ++p) {
      const int dl = p * 16 + (tid >> 4);
      const int tt = (tid & 15) * 8;
      u16x8 o = *(const u16x8*)(smem + dl * 152 + tt);
      *(u16x8*)(out2 + ((long)h * 128 + dh * 64 + dl) * 2048 + bm + tt) = o;
    }
  }
}

// ---------------- oct GEMM, m97 structure: 128x128, BK=64, single-buffer ----------------
template <int MODE>
__global__ __launch_bounds__(256, 3) void oct_gemm128(
    const u16* __restrict__ A, const u16* __restrict__ WtB,
    void* __restrict__ out0,
    int K, int lda, int ldo,
    int slab_shift, int bs_shift, long wslab, long oslab, long acolslab)
{
  __shared__ u16 smem[16384];
  const int NT = K >> 6;
  const int BS = 1 << bs_shift;
  const long wblk = (long)BS * BS;

  const int nwg = gridDim.x * gridDim.y;
  const int lin = blockIdx.y * gridDim.x + blockIdx.x;
  const int swz = (lin & 7) * (nwg >> 3) + (lin >> 3);
  const int bx = swz % gridDim.x, by = swz / gridDim.x;

  const int nglob = bx * 128;
  const int z = nglob >> slab_shift;
  const int np = nglob & ((1 << slab_shift) - 1);
  const int bi = np >> bs_shift;
  const int nsub = np & (BS - 1);
  const int bm = by * 128;
  const u16* Wt = WtB + (long)z * wslab;
  const long acol0 = (long)z * acolslab;

  const int tid = threadIdx.x;
  const int lane = tid & 63, w = tid >> 6;
  const int l15 = lane & 15, lg = lane >> 4;
  const int wm = w >> 1, wn = w & 1;
  const int srow = lane >> 3;
  const int sgr  = (lane & 7) ^ srow;

  f32x4 acc[4][4];
#pragma unroll
  for (int a = 0; a < 4; a++)
#pragma unroll
    for (int b = 0; b < 4; b++) acc[a][b] = f32x4{0.f, 0.f, 0.f, 0.f};

  for (int t = 0; t < NT; ++t) {
    const int k0 = t << 6;
    const int bj = k0 >> bs_shift;
    const int widx = bi ^ bj;
    const unsigned xm = (c_osgn[bj * 8 + widx] < 0.f) ? 0x80008000u : 0u;
    const u16* Wsrc = Wt + (long)widx * wblk + (k0 & (BS - 1));

#pragma unroll
    for (int i = 0; i < 4; i++) {
      const int r = (w * 4 + i) * 8;
      load16_lds(A + (long)(bm + r + srow) * lda + acol0 + k0 + sgr * 8,
                 (void*)(smem + r * 64));
    }
#pragma unroll
    for (int i = 0; i < 4; i++) {
      const int r = (w * 4 + i) * 8;
      load16_lds(Wsrc + (long)(nsub + r + srow) * BS + sgr * 8,
                 (void*)(smem + 8192 + r * 64));
    }
    __syncthreads();

#pragma unroll
    for (int kk = 0; kk < 64; kk += 32) {
      const int gsw = (((kk >> 3) + lg) ^ (l15 & 7)) * 8;
      uint4 a4[4];
      bf16x8 bF[4];
#pragma unroll
      for (int mt = 0; mt < 4; mt++)
        a4[mt] = *(const uint4*)(smem + (wm * 64 + mt * 16 + l15) * 64 + gsw);
      if (xm) {
#pragma unroll
        for (int mt = 0; mt < 4; mt++) {
          a4[mt].x ^= xm; a4[mt].y ^= xm; a4[mt].z ^= xm; a4[mt].w ^= xm;
        }
      }
#pragma unroll
      for (int nt = 0; nt < 4; nt++)
        bF[nt] = *(const bf16x8*)(smem + 8192 + (wn * 64 + nt * 16 + l15) * 64 + gsw);
#pragma unroll
      for (int mt = 0; mt < 4; mt++)
#pragma unroll
        for (int nt = 0; nt < 4; nt++)
          acc[mt][nt] = __builtin_amdgcn_mfma_f32_16x16x32_bf16(
              *(const bf16x8*)&a4[mt], bF[nt], acc[mt][nt], 0, 0, 0);
    }
    __syncthreads();
  }

#pragma unroll
  for (int mt = 0; mt < 4; mt++)
#pragma unroll
    for (int nt = 0; nt < 4; nt++)
#pragma unroll
      for (int j = 0; j < 4; j++) {
        const int row = bm + wm * 64 + mt * 16 + 4 * lg + j;
        const int col = np + wn * 64 + nt * 16 + l15;
        const float v = acc[mt][nt][j];
        if constexpr (MODE == 0)
          ((u16*)out0)[(long)z * oslab + (long)row * ldo + col] = f2bf(v);
        else
          ((float*)out0)[(long)row * ldo + col] = v;
      }
}

// ---------------- flash attention v5: fixed-max softmax + lsum via ones-MFMA ----------------
__global__ __launch_bounds__(256, 2) void attn5(
    const u16* __restrict__ qR, const u16* __restrict__ kR,
    const u16* __restrict__ vT, u16* __restrict__ y)
{
  const int bid = blockIdx.x;
  const int h = bid & 31;
  const int qb = 31 - (bid >> 5);        // longest blocks dispatched first
  const int q0 = qb * 64;

  const int tid = threadIdx.x;
  const int lane = tid & 63, w = tid >> 6;
  const int l15 = lane & 15, lg = lane >> 4;

  __shared__ u16 Ks[2][64][128];
  __shared__ u16 Vs[2][128][64];
  __shared__ u16 Ps[4][16][64];

  auto stageK = [&](int kb, int buf) {
    const long kbase = (long)h * 2048 + (long)kb * 64;
#pragma unroll
    for (int i = 0; i < 4; i++) {
      const int j = w * 4 + i;
      const int row = j * 4 + (lane >> 4);
      const int sg = (lane & 15) ^ (row & 7);
      load16_lds(kR + (kbase + row) * 128 + sg * 8, (void*)&Ks[buf][j * 4][0]);
    }
  };
  auto stageV = [&](int kb, int buf) {
    const long vbase = (long)h * 128 * 2048 + (long)kb * 64;
#pragma unroll
    for (int i = 0; i < 4; i++) {
      const int j = w * 4 + i;
      const int row = j * 8 + (lane >> 3);
      const int sg = (lane & 7) ^ (row & 7);
      load16_lds(vT + vbase + (long)row * 2048 + sg * 8, (void*)&Vs[buf][j * 8][0]);
    }
  };

  stageK(0, 0);
  stageV(0, 0);

  bf16x8 aQ[4];
  {
    const long qbase = ((long)h * 2048 + q0 + w * 16 + l15) * 128;
#pragma unroll
    for (int c = 0; c < 4; c++)
      aQ[c] = *(const bf16x8*)(qR + qbase + 32 * c + 8 * lg);
  }

  bf16x8 ones;
#pragma unroll
  for (int j = 0; j < 8; j++) ones[j] = (__bf16)1.0f;

  f32x4 Y[8], LS;
#pragma unroll
  for (int dt = 0; dt < 8; dt++) Y[dt] = f32x4{0.f, 0.f, 0.f, 0.f};
  LS = f32x4{0.f, 0.f, 0.f, 0.f};

  const float scale = 0.08838834764831845f;   // 1/sqrt(128)
  const int nkb = qb + 1;

  for (int kb = 0; kb < nkb; kb++) {
    const int buf = kb & 1;
    const int k0 = kb * 64;
    if (kb + 1 < nkb) { stageK(kb + 1, buf ^ 1); stageV(kb + 1, buf ^ 1); }
    if (kb + 1 < nkb) asm volatile("s_waitcnt vmcnt(8)" ::: "memory");
    else              asm volatile("s_waitcnt vmcnt(0)" ::: "memory");
    __builtin_amdgcn_s_barrier();
    asm volatile("" ::: "memory");

    // ---- QK^T ----
    f32x4 S[4];
#pragma unroll
    for (int ks = 0; ks < 4; ks++) S[ks] = f32x4{0.f, 0.f, 0.f, 0.f};
#pragma unroll
    for (int c = 0; c < 4; c++) {
      bf16x8 bK[4];
#pragma unroll
      for (int ks = 0; ks < 4; ks++)
        bK[ks] = *(const bf16x8*)&Ks[buf][ks * 16 + l15][(((4 * c + lg) ^ (l15 & 7)) * 8)];
#pragma unroll
      for (int ks = 0; ks < 4; ks++)
        S[ks] = __builtin_amdgcn_mfma_f32_16x16x32_bf16(aQ[c], bK[ks], S[ks], 0, 0, 0);
    }

    // ---- fixed-max softmax: P = exp(S*scale - 32), masked -> 0 ----
    {
      const int qrow0 = q0 + w * 16 + 4 * lg;
#pragma unroll
      for (int ks = 0; ks < 4; ks++) {
        const int kg = k0 + ks * 16 + l15;
#pragma unroll
        for (int rr = 0; rr < 4; rr++) {
          const float e = __expf(fmaf(S[ks][rr], scale, -32.f));
          S[ks][rr] = (kg > qrow0 + rr) ? 0.f : e;
        }
      }
#pragma unroll
      for (int ks = 0; ks < 4; ks++)
#pragma unroll
        for (int rr = 0; rr < 4; rr++) {
          const int row = 4 * lg + rr;
          const int G = (2 * ks + (l15 >> 3)) ^ (row & 7);
          Ps[w][row][G * 8 + (l15 & 7)] = f2bf(S[ks][rr]);
        }
    }

    // ---- PV + lsum ----
#pragma unroll
    for (int kk = 0; kk < 2; kk++) {
      const int pg = ((4 * kk + lg) ^ (l15 & 7)) * 8;
      bf16x8 pF = *(const bf16x8*)&Ps[w][l15][pg];
#pragma unroll
      for (int dt = 0; dt < 8; dt++) {
        bf16x8 vF = *(const bf16x8*)&Vs[buf][dt * 16 + l15][pg];
        Y[dt] = __builtin_amdgcn_mfma_f32_16x16x32_bf16(pF, vF, Y[dt], 0, 0, 0);
      }
      LS = __builtin_amdgcn_mfma_f32_16x16x32_bf16(pF, ones, LS, 0, 0, 0);
    }
    asm volatile("" ::: "memory");
    __builtin_amdgcn_s_barrier();
    asm volatile("" ::: "memory");
  }

  // ---- normalize + write ----
  float inv[4];
#pragma unroll
  for (int rr = 0; rr < 4; rr++) inv[rr] = 1.0f / LS[rr];
#pragma unroll
  for (int dt = 0; dt < 8; dt++)
#pragma unroll
    for (int rr = 0; rr < 4; rr++)
      y[(long)(q0 + w * 16 + 4 * lg + rr) * 4096 + h * 128 + dt * 16 + l15] =
          f2bf(Y[dt][rr] * inv[rr]);
}

// ---------------- host ----------------
extern "C" void kernel_launch(void* const* d_in, const int* in_sizes, int n_in,
                              void* d_out, int out_size, void* d_ws, size_t ws_size,
                              hipStream_t stream) {
  const float* x    = (const float*)d_in[0];
  const float* Wq   = (const float*)d_in[1];
  const float* Wk   = (const float*)d_in[2];
  const float* Wv   = (const float*)d_in[3];
  const float* Wo   = (const float*)d_in[4];
  const float* Wm   = (const float*)d_in[5];
  const float* beta = (const float*)d_in[6];
  const float* fc   = (const float*)d_in[7];
  const float* fs   = (const float*)d_in[8];
  float* out = (float*)d_out;

  const long TC = 2048L * 4096L;     // 8,388,608
  const long WSZ = 8L * 512 * 512;   // 2,097,152
  u16* ws  = (u16*)d_ws;
  u16* xb  = ws;                     // [T][C] bf16 x           (later reused as y_att)
  u16* wt  = ws + TC;                // Wq,Wk,Wv,Wo transposed bf16
  u16* wmt = wt + 4 * WSZ;           // mixer W transposed*beta
  u16* g3  = wmt + 131072L;          // scratch (ymix)
  u16* r3  = g3 + 3 * TC;            // qR, kR [H][T][D]; vT [H][D][T]
  u16* yatt = xb;
  u16* ymix = g3;

  conv_f32_bf16_vec<<<TC / 4 / 256, 256, 0, stream>>>(x, xb);
  transpose_w4<<<dim3(8, 8, 32), 256, 0, stream>>>(Wq, Wk, Wv, Wo, wt, WSZ);
  transpose_wm<<<512, 256, 0, stream>>>(Wm, beta, wmt);

  // fused q,k,v GEMM: A staged once, 3 B tiles, 96 MFMA/barrier; rope + v-transpose fused
  oct_gemmQKV<<<dim3(32, 16), 256, 0, stream>>>(
      xb, wt, r3, r3 + TC, r3 + 2 * TC, fc, fs, WSZ);

  attn5<<<1024, 256, 0, stream>>>(r3, r3 + TC, r3 + 2 * TC, yatt);

  // mixer: BS=128, K=1024, N-slab 1024 per group, A col offset 1024 per group
  oct_gemm128<0><<<dim3(32, 16), 256, 0, stream>>>(
      yatt, wmt, (void*)ymix,
      1024, 4096, 4096, 10, 7, 0L, 1024L, 1024L);

  // final oct_linear with Wo -> f32 out
  oct_gemm128<2><<<dim3(32, 16), 256, 0, stream>>>(
      ymix, wt + 3 * WSZ, (void*)out,
      4096, 4096, 4096, 12, 9, 0L, 0L, 0L);
}